// Round 1
// baseline (2234.775 us; speedup 1.0000x reference)
//
#include <hip/hip_runtime.h>

using f32x4 = __attribute__((ext_vector_type(4))) float;
using s16x8 = __attribute__((ext_vector_type(8))) short;

#define NROWS 100000

__device__ __forceinline__ unsigned short f2bf(float f) {
    unsigned int u = __float_as_uint(f);
    u = (u + 0x7fffu + ((u >> 16) & 1u)) >> 16;
    return (unsigned short)u;
}

__device__ __forceinline__ float sigm(float x) { return 1.0f / (1.0f + __expf(-x)); }

// ---------------- pack kernels ----------------

// W (K x Nn row-major f32) -> Wt (Nn x K row-major bf16), scale folded.
__global__ void pack_w(const float* __restrict__ W, unsigned short* __restrict__ Wt,
                       int K, int Nn, float scale) {
    int idx = blockIdx.x * blockDim.x + threadIdx.x;
    if (idx >= K * Nn) return;
    int n = idx / K, k = idx - n * K;
    Wt[idx] = f2bf(W[(size_t)k * Nn + n] * scale);
}

// features (N x 640 f32, vector part interleaved 256+3j+d) ->
// Xs (N x 640 bf16, de-interleaved [s 256 | d0 128 | d1 128 | d2 128])
__global__ void pack_x(const float* __restrict__ F, unsigned short* __restrict__ Xs) {
    size_t total = (size_t)NROWS * 640;
    size_t stride = (size_t)gridDim.x * blockDim.x;
    for (size_t idx = (size_t)blockIdx.x * blockDim.x + threadIdx.x; idx < total; idx += stride) {
        size_t n = idx / 640;
        int co = (int)(idx - n * 640);
        int ci = (co < 256) ? co : (256 + 3 * ((co - 256) & 127) + ((co - 256) >> 7));
        Xs[idx] = f2bf(F[n * 640 + ci]);
    }
}

// ---------------- GEMM helper ----------------
// Computes CNT 16-wide output tiles (acc[ABASE..ABASE+CNT) x {m0,m1}) for 32 rows
// starting at row0. A = X rows (M x K slice at column kb, row stride cin),
// B^T = W rows (Wt is (N,K) row-major, rows wrow0 + i*16 ...).
template<int TPW, int CNT, int ABASE>
__device__ __forceinline__ void gemm_seg(f32x4 (&acc)[TPW][2],
        const unsigned short* X, int cin, int row0, int lane,
        const unsigned short* W, int K, int kb, int wrow0) {
    const unsigned short* xp = X + (size_t)(row0 + (lane & 15)) * cin + kb + ((lane >> 4) << 3);
    const unsigned short* wp = W + (size_t)(wrow0 + (lane & 15)) * K + ((lane >> 4) << 3);
    const size_t xstep = (size_t)cin << 4;  // 16 rows
    for (int k = 0; k < K; k += 32) {
        s16x8 a0 = *(const s16x8*)(xp + k);
        s16x8 a1 = *(const s16x8*)(xp + xstep + k);
        #pragma unroll
        for (int i = 0; i < CNT; ++i) {
            s16x8 b = *(const s16x8*)(wp + (size_t)(i * 16) * K + k);
            acc[ABASE + i][0] = __builtin_amdgcn_mfma_f32_16x16x32_bf16(a0, b, acc[ABASE + i][0], 0, 0, 0);
            acc[ABASE + i][1] = __builtin_amdgcn_mfma_f32_16x16x32_bf16(a1, b, acc[ABASE + i][1], 0, 0, 0);
        }
    }
}

// ---------------- layer 1/2: irlin + gate ----------------
// Xin: N x (K0+3K1) bf16 de-interleaved.  Out: N x 1280 bf16 de-interleaved
// [silu 512 | d0 256 | d1 256 | d2 256].  May be in-place (L2): all global
// reads complete before first __syncthreads, writes only after.
template<int K0, int K1>
__global__ __launch_bounds__(512, 2) void layer12_kernel(
        const unsigned short* Xin, const unsigned short* __restrict__ W0t,
        const unsigned short* __restrict__ W1t, unsigned short* Out) {
    constexpr int CIN = K0 + 3 * K1;
    __shared__ float gbuf[32][256];
    const int tid = threadIdx.x, wid = tid >> 6, lane = tid & 63;
    const int row0 = blockIdx.x * 32;

    f32x4 acc[12][2];
    const f32x4 vz = {0.f, 0.f, 0.f, 0.f};
    #pragma unroll
    for (int i = 0; i < 12; ++i) { acc[i][0] = vz; acc[i][1] = vz; }

    // tiles: scalar 0..47 (W0t rows t*16), d0 48..63, d1 64..79, d2 80..95 (W1t rows j*16)
    switch (wid) {
    case 0: gemm_seg<12,12,0>(acc, Xin, CIN, row0, lane, W0t, K0, 0, 0); break;
    case 1: gemm_seg<12,12,0>(acc, Xin, CIN, row0, lane, W0t, K0, 0, 192); break;
    case 2: gemm_seg<12,12,0>(acc, Xin, CIN, row0, lane, W0t, K0, 0, 384); break;
    case 3: gemm_seg<12,12,0>(acc, Xin, CIN, row0, lane, W0t, K0, 0, 576); break;
    case 4: gemm_seg<12,12,0>(acc, Xin, CIN, row0, lane, W1t, K1, K0, 0); break;
    case 5: gemm_seg<12,4,0>(acc, Xin, CIN, row0, lane, W1t, K1, K0, 192);
            gemm_seg<12,8,4>(acc, Xin, CIN, row0, lane, W1t, K1, K0 + K1, 0); break;
    case 6: gemm_seg<12,8,0>(acc, Xin, CIN, row0, lane, W1t, K1, K0 + K1, 128);
            gemm_seg<12,4,8>(acc, Xin, CIN, row0, lane, W1t, K1, K0 + 2 * K1, 0); break;
    case 7: gemm_seg<12,12,0>(acc, Xin, CIN, row0, lane, W1t, K1, K0 + 2 * K1, 64); break;
    }
    __syncthreads();  // all reads of Xin done (needed for in-place L2)

    const int colg = lane & 15, rbase = (lane >> 4) * 4;
    // phase A: silu part -> global, sigmoid gates -> LDS
    #pragma unroll
    for (int i = 0; i < 12; ++i) {
        int t = wid * 12 + i;
        if (t < 32) {
            #pragma unroll
            for (int mm = 0; mm < 2; ++mm)
            #pragma unroll
            for (int r = 0; r < 4; ++r) {
                float v = acc[i][mm][r];
                int row = mm * 16 + rbase + r;
                Out[(size_t)(row0 + row) * 1280 + t * 16 + colg] = f2bf(v * sigm(v));
            }
        } else if (t < 48) {
            #pragma unroll
            for (int mm = 0; mm < 2; ++mm)
            #pragma unroll
            for (int r = 0; r < 4; ++r) {
                float v = acc[i][mm][r];
                gbuf[mm * 16 + rbase + r][(t - 32) * 16 + colg] = sigm(v);
            }
        }
    }
    __syncthreads();
    // phase B: gated vector part -> global
    #pragma unroll
    for (int i = 0; i < 12; ++i) {
        int t = wid * 12 + i;
        if (t >= 48) {
            int u = t - 48, d = u >> 4, jj = ((u & 15) << 4) + colg;
            #pragma unroll
            for (int mm = 0; mm < 2; ++mm)
            #pragma unroll
            for (int r = 0; r < 4; ++r) {
                int row = mm * 16 + rbase + r;
                float v = acc[i][mm][r] * gbuf[row][jj];
                Out[(size_t)(row0 + row) * 1280 + 512 + d * 256 + jj] = f2bf(v);
            }
        }
    }
}

// ---------------- layer 3 + bypass + stats ----------------
// G2: N x 1280 bf16.  Xs: N x 640 bf16.  OutF: N x 640 f32 de-interleaved
// [s 256 | d0 128 | d1 128 | d2 128] -- OVERWRITES G2's rows (same byte span).
// stats: [0,256) sum_s, [256,512) sum_s2, [512,896) sum_v2 per (d,j).
__global__ __launch_bounds__(512, 2) void layer3_kernel(
        const unsigned short* G2, const unsigned short* __restrict__ W0t,
        const unsigned short* __restrict__ W1t,
        const unsigned short* __restrict__ Xs,
        const unsigned short* __restrict__ Wb0, const unsigned short* __restrict__ Wb1,
        float* OutF, float* __restrict__ stats) {
    const int tid = threadIdx.x, wid = tid >> 6, lane = tid & 63;
    const int row0 = blockIdx.x * 32;

    f32x4 acc[5][2];
    const f32x4 vz = {0.f, 0.f, 0.f, 0.f};
    #pragma unroll
    for (int i = 0; i < 5; ++i) { acc[i][0] = vz; acc[i][1] = vz; }

    // tiles: scalar 0..15, d0 16..23, d1 24..31, d2 32..39
    switch (wid) {
    case 0: gemm_seg<5,5,0>(acc, G2, 1280, row0, lane, W0t, 512, 0, 0);
            gemm_seg<5,5,0>(acc, Xs, 640, row0, lane, Wb0, 256, 0, 0); break;
    case 1: gemm_seg<5,5,0>(acc, G2, 1280, row0, lane, W0t, 512, 0, 80);
            gemm_seg<5,5,0>(acc, Xs, 640, row0, lane, Wb0, 256, 0, 80); break;
    case 2: gemm_seg<5,5,0>(acc, G2, 1280, row0, lane, W0t, 512, 0, 160);
            gemm_seg<5,5,0>(acc, Xs, 640, row0, lane, Wb0, 256, 0, 160); break;
    case 3: gemm_seg<5,1,0>(acc, G2, 1280, row0, lane, W0t, 512, 0, 240);
            gemm_seg<5,4,1>(acc, G2, 1280, row0, lane, W1t, 256, 512, 0);
            gemm_seg<5,1,0>(acc, Xs, 640, row0, lane, Wb0, 256, 0, 240);
            gemm_seg<5,4,1>(acc, Xs, 640, row0, lane, Wb1, 128, 256, 0); break;
    case 4: gemm_seg<5,4,0>(acc, G2, 1280, row0, lane, W1t, 256, 512, 64);
            gemm_seg<5,1,4>(acc, G2, 1280, row0, lane, W1t, 256, 768, 0);
            gemm_seg<5,4,0>(acc, Xs, 640, row0, lane, Wb1, 128, 256, 64);
            gemm_seg<5,1,4>(acc, Xs, 640, row0, lane, Wb1, 128, 384, 0); break;
    case 5: gemm_seg<5,5,0>(acc, G2, 1280, row0, lane, W1t, 256, 768, 16);
            gemm_seg<5,5,0>(acc, Xs, 640, row0, lane, Wb1, 128, 384, 16); break;
    case 6: gemm_seg<5,2,0>(acc, G2, 1280, row0, lane, W1t, 256, 768, 96);
            gemm_seg<5,3,2>(acc, G2, 1280, row0, lane, W1t, 256, 1024, 0);
            gemm_seg<5,2,0>(acc, Xs, 640, row0, lane, Wb1, 128, 384, 96);
            gemm_seg<5,3,2>(acc, Xs, 640, row0, lane, Wb1, 128, 512, 0); break;
    case 7: gemm_seg<5,5,0>(acc, G2, 1280, row0, lane, W1t, 256, 1024, 48);
            gemm_seg<5,5,0>(acc, Xs, 640, row0, lane, Wb1, 128, 512, 48); break;
    }
    __syncthreads();  // all reads of G2 rows done before overwriting

    const int colg = lane & 15, rbase = (lane >> 4) * 4;
    #pragma unroll
    for (int i = 0; i < 5; ++i) {
        int t = wid * 5 + i;
        bool isScalar = t < 16;
        int col;
        if (isScalar) col = t * 16 + colg;
        else { int u = t - 16; col = 256 + (u >> 3) * 128 + ((u & 7) << 4) + colg; }
        float s0 = 0.f, s1 = 0.f;
        #pragma unroll
        for (int mm = 0; mm < 2; ++mm)
        #pragma unroll
        for (int r = 0; r < 4; ++r) {
            float v = acc[i][mm][r];
            OutF[(size_t)(row0 + mm * 16 + rbase + r) * 640 + col] = v;
            s0 += v; s1 += v * v;
        }
        s0 += __shfl_xor(s0, 16); s0 += __shfl_xor(s0, 32);
        s1 += __shfl_xor(s1, 16); s1 += __shfl_xor(s1, 32);
        if (lane < 16) {
            if (isScalar) atomicAdd(&stats[col], s0);
            atomicAdd(&stats[256 + col], s1);
        }
    }
}

// ---------------- batchnorm ----------------
__global__ void bn_finalize(const float* __restrict__ stats, const float* __restrict__ bnw,
                            const float* __restrict__ bnb, float* __restrict__ params) {
    int c = threadIdx.x;
    const float invN = 1.0f / (float)NROWS;
    if (c < 256) {
        float mean = stats[c] * invN;
        float var = stats[256 + c] * invN - mean * mean;
        float sc = rsqrtf(var + 1e-5f) * bnw[c];
        params[c] = sc;
        params[256 + c] = bnb[c] - mean * sc;
    } else if (c < 384) {
        int j = c - 256;
        float sv = stats[512 + j] + stats[640 + j] + stats[768 + j];
        float vinv = rsqrtf(sv * (invN * (1.0f / 3.0f)) + 1e-5f) * bnw[256 + j];
        params[512 + j] = vinv;
    }
}

__global__ void bn_apply(const float* __restrict__ OutF, const float* __restrict__ params,
                         float* __restrict__ out) {
    size_t total = (size_t)NROWS * 640;
    size_t stride = (size_t)gridDim.x * blockDim.x * 4;
    for (size_t base = ((size_t)blockIdx.x * blockDim.x + threadIdx.x) * 4; base < total; base += stride) {
        size_t n = base / 640;
        int c0 = (int)(base - n * 640);
        const float* rowp = OutF + n * 640;
        f32x4 o;
        #pragma unroll
        for (int q = 0; q < 4; ++q) {
            int c = c0 + q;
            if (c < 256) {
                o[q] = rowp[c] * params[c] + params[256 + c];
            } else {
                int u = c - 256; int j = u / 3; int d = u - 3 * j;
                o[q] = rowp[256 + d * 128 + j] * params[512 + j];
            }
        }
        *(f32x4*)(out + base) = o;
    }
}

// ---------------- launch ----------------
extern "C" void kernel_launch(void* const* d_in, const int* in_sizes, int n_in,
                              void* d_out, int out_size, void* d_ws, size_t ws_size,
                              hipStream_t stream) {
    const float* features = (const float*)d_in[0];
    const float* l1w0 = (const float*)d_in[1];
    const float* l1w1 = (const float*)d_in[2];
    const float* l2w0 = (const float*)d_in[3];
    const float* l2w1 = (const float*)d_in[4];
    const float* l3w0 = (const float*)d_in[5];
    const float* l3w1 = (const float*)d_in[6];
    const float* bw0  = (const float*)d_in[7];
    const float* bw1  = (const float*)d_in[8];
    const float* bnw  = (const float*)d_in[9];
    const float* bnb  = (const float*)d_in[10];
    float* out = (float*)d_out;
    char* ws = (char*)d_ws;

    unsigned short* W10 = (unsigned short*)(ws + 0);        // 768x256
    unsigned short* W11 = (unsigned short*)(ws + 393216);   // 256x128
    unsigned short* W20 = (unsigned short*)(ws + 458752);   // 768x512
    unsigned short* W21 = (unsigned short*)(ws + 1245184);  // 256x256
    unsigned short* W30 = (unsigned short*)(ws + 1376256);  // 256x512
    unsigned short* W31 = (unsigned short*)(ws + 1638400);  // 128x256
    unsigned short* WB0 = (unsigned short*)(ws + 1703936);  // 256x256
    unsigned short* WB1 = (unsigned short*)(ws + 1835008);  // 128x128
    float* stats  = (float*)(ws + 1867776);                 // 896 f32
    float* params = (float*)(ws + 1871360);                 // 640 f32
    unsigned short* Xs = (unsigned short*)(ws + 2097152);   // 100000x640 bf16
    unsigned short* G  = (unsigned short*)(ws + 130097152); // 100000x1280 bf16 (reused as OutF f32)
    float* Gf = (float*)G;

    hipMemsetAsync(stats, 0, 896 * sizeof(float), stream);

    const float s_inv16   = 0.0625f;               // 1/sqrt(256)
    const float s_inv128  = 0.08838834764831845f;  // 1/sqrt(128)
    const float s_inv512  = 0.04419417382415922f;  // 1/sqrt(512)

    pack_w<<<768, 256, 0, stream>>>(l1w0, W10, 256, 768, s_inv16);
    pack_w<<<128, 256, 0, stream>>>(l1w1, W11, 128, 256, s_inv128);
    pack_w<<<1536, 256, 0, stream>>>(l2w0, W20, 512, 768, s_inv512);
    pack_w<<<256, 256, 0, stream>>>(l2w1, W21, 256, 256, s_inv16);
    pack_w<<<512, 256, 0, stream>>>(l3w0, W30, 512, 256, s_inv512);
    pack_w<<<128, 256, 0, stream>>>(l3w1, W31, 256, 128, s_inv16);
    pack_w<<<256, 256, 0, stream>>>(bw0, WB0, 256, 256, s_inv16);
    pack_w<<<64, 256, 0, stream>>>(bw1, WB1, 128, 128, s_inv128);
    pack_x<<<8192, 256, 0, stream>>>(features, Xs);

    layer12_kernel<256, 128><<<3125, 512, 0, stream>>>(Xs, W10, W11, G);
    layer12_kernel<512, 256><<<3125, 512, 0, stream>>>(G, W20, W21, G);
    layer3_kernel<<<3125, 512, 0, stream>>>(G, W30, W31, Xs, WB0, WB1, Gf, stats);
    bn_finalize<<<1, 512, 0, stream>>>(stats, bnw, bnb, params);
    bn_apply<<<4096, 256, 0, stream>>>(Gf, params, out);
}